// Round 20
// baseline (96.229 us; speedup 1.0000x reference)
//
#include <hip/hip_runtime.h>
#include <hip/hip_bf16.h>

#define NN   50000
#define NE   800000
#define NBK  200    // partition blocks, 4000 edges each (200*4000 == NE exactly)
#define EPB  4000
#define NH   196    // MSD buckets: h = dst >> 8, h in [0,196)

typedef __attribute__((ext_vector_type(8))) short short8;
typedef __attribute__((ext_vector_type(4))) float f32x4;
typedef __attribute__((ext_vector_type(2))) float f32x2;

static __device__ __forceinline__ ushort f2bf(float f) {
    union { float f; unsigned u; } v; v.f = f;
    unsigned r = v.u + 0x7fffu + ((v.u >> 16) & 1u);   // round-to-nearest-even
    return (ushort)(r >> 16);
}
static __device__ __forceinline__ float bf2f(ushort h) {
    union { unsigned u; float f; } v; v.u = ((unsigned)h) << 16;
    return v.f;
}

// exclusive scan of 256 values; on return s[] holds INCLUSIVE scan.
static __device__ __forceinline__ int exscan256(int* s, int tid, int v) {
    __syncthreads();
    s[tid] = v;
    __syncthreads();
    #pragma unroll
    for (int off = 1; off < 256; off <<= 1) {
        int a = (tid >= off) ? s[tid - off] : 0;
        __syncthreads();
        s[tid] += a;
        __syncthreads();
    }
    return s[tid] - v;
}

// ---------------- hist1: pure per-block histogram of h=dst>>8 ----------------
// 200 blocks x 256. Block b owns edges [b*4000, b*4000+4000).
__global__ __launch_bounds__(256) void hist1_k(
    const int* __restrict__ dst, int* __restrict__ ghist)
{
    __shared__ int hist[256];
    int tid = threadIdx.x, b = blockIdx.x;
    hist[tid] = 0;
    __syncthreads();
    int eb = b * EPB;
    #pragma unroll
    for (int j = 0; j < 16; ++j) {
        int o = j * 256 + tid;
        if (o < EPB) atomicAdd(&hist[dst[eb + o] >> 8], 1);
    }
    __syncthreads();
    ghist[b * 256 + tid] = hist[tid];
}

// ---------------- scan1: per-digit exclusive scan over 200 blocks + cvtx + weight prep ----------------
// 196 blocks; block h scans ghist[b][h] over b (single 256-pass since 200<256).
__global__ __launch_bounds__(256) void scan1_k(
    const int* __restrict__ ghist, int* __restrict__ gbase,
    int* __restrict__ dtot,
    const float* __restrict__ x, ushort* __restrict__ xb,
    unsigned* __restrict__ x8w,
    const float* __restrict__ Wl0, const float* __restrict__ Wr0,
    const float* __restrict__ Wl1, const float* __restrict__ Wr1,
    ushort* __restrict__ wbt0, ushort* __restrict__ wbt1)
{
    __shared__ int s[256];
    int tid = threadIdx.x, h = blockIdx.x;
    int gid = h * 256 + tid;

    if (gid < 2048) {
        {   // dense0 image
            int c = gid;
            int n  = c >> 4;
            int kc = (c & 15) * 8;
            const float* wsrc = (kc < 64) ? (Wl0 + n * 64 + kc) : (Wr0 + n * 64 + (kc - 64));
            float4 f0 = *(const float4*)(wsrc);
            float4 f1 = *(const float4*)(wsrc + 4);
            short8 v;
            v[0] = f2bf(f0.x); v[1] = f2bf(f0.y); v[2] = f2bf(f0.z); v[3] = f2bf(f0.w);
            v[4] = f2bf(f1.x); v[5] = f2bf(f1.y); v[6] = f2bf(f1.z); v[7] = f2bf(f1.w);
            int byte = (n * 256 + kc * 2) ^ ((n & 7) << 4);
            *(short8*)((char*)wbt0 + byte) = v;
        }
        #pragma unroll
        for (int rep = 0; rep < 2; ++rep) {   // dense1 half-images
            int c = gid + rep * 2048;
            int n  = c >> 5;
            int kc = (c & 31) * 8;
            int hh = (kc >= 128);
            int kk = kc - hh * 128;
            const float* wsrc = hh ? (Wr1 + n * 128 + kk) : (Wl1 + n * 128 + kk);
            float4 f0 = *(const float4*)(wsrc);
            float4 f1 = *(const float4*)(wsrc + 4);
            short8 v;
            v[0] = f2bf(f0.x); v[1] = f2bf(f0.y); v[2] = f2bf(f0.z); v[3] = f2bf(f0.w);
            v[4] = f2bf(f1.x); v[5] = f2bf(f1.y); v[6] = f2bf(f1.z); v[7] = f2bf(f1.w);
            int byte = hh * 32768 + ((n * 256 + kk * 2) ^ ((n & 7) << 4));
            *(short8*)((char*)wbt1 + byte) = v;
        }
    }

    // per-digit scan (one pass, NBK=200 < 256)
    int v = (tid < NBK) ? ghist[tid * 256 + h] : 0;
    int ex = exscan256(s, tid, v);
    if (tid < NBK) gbase[tid * 256 + h] = ex;
    if (tid == 0) dtot[h] = s[255];

    // cvtx: 16 guarded rounds over 800,000 float4-groups (196*256 = 50176 threads)
    #pragma unroll
    for (int r = 0; r < 16; ++r) {
        int idx = r * 50176 + gid;
        if (idx < 800000) {
            float4 f = ((const float4*)x)[idx];
            ushort4 o;
            o.x = f2bf(f.x); o.y = f2bf(f.y); o.z = f2bf(f.z); o.w = f2bf(f.w);
            ((ushort4*)xb)[idx] = o;
            unsigned q = 0;
            q = __builtin_amdgcn_cvt_pk_fp8_f32(f.x, f.y, q, false);
            q = __builtin_amdgcn_cvt_pk_fp8_f32(f.z, f.w, q, true);
            x8w[idx] = q;
        }
    }
}

// ---------------- scat1: partition packed edges by h into buf1 (LDS local sort) ----------------
__global__ __launch_bounds__(256) void scat1_k(
    const int* __restrict__ src, const int* __restrict__ dst,
    const int* __restrict__ gbase, const int* __restrict__ dtot,
    unsigned* __restrict__ buf1)
{
    __shared__ int sc[256], hist[256], lbase[256], cur[256], dbase[256], gb[256];
    __shared__ unsigned sorted[EPB];
    int tid = threadIdx.x, b = blockIdx.x;
    hist[tid] = 0;
    gb[tid] = gbase[b * 256 + tid];
    int dv = (tid < NH) ? dtot[tid] : 0;
    int eb = b * EPB;
    unsigned k[16]; int dg[16];
    __syncthreads();
    #pragma unroll
    for (int j = 0; j < 16; ++j) {
        int o = j * 256 + tid;
        dg[j] = -1;
        if (o < EPB) {
            int e = eb + o;
            int d_ = dst[e];
            k[j]  = ((unsigned)d_ << 16) | (unsigned)src[e];
            dg[j] = d_ >> 8;
            atomicAdd(&hist[dg[j]], 1);
        }
    }
    __syncthreads();
    int ex = exscan256(sc, tid, hist[tid]);
    lbase[tid] = ex; cur[tid] = ex;
    int dbx = exscan256(sc, tid, dv);
    dbase[tid] = dbx;
    __syncthreads();
    #pragma unroll
    for (int j = 0; j < 16; ++j) {
        if (dg[j] >= 0) {
            int lr = atomicAdd(&cur[dg[j]], 1);
            sorted[lr] = k[j];
        }
    }
    __syncthreads();
    #pragma unroll
    for (int j = 0; j < 16; ++j) {
        int i = j * 256 + tid;
        if (i < EPB) {
            unsigned kk = sorted[i];
            int dig = (int)(kk >> 24);          // == dst >> 8
            int pos = dbase[dig] + gb[dig] + (i - lbase[dig]);
            buf1[pos] = kk;
        }
    }
}

// ---------------- build: per-bucket LDS count/rank -> rowptr + nbr16 ----------------
// 196 blocks; bucket h covers nodes [h*256, h*256+256).
__global__ __launch_bounds__(256) void build_k(
    const unsigned* __restrict__ buf1, const int* __restrict__ dtot,
    int* __restrict__ rowptr, ushort* __restrict__ nbr16)
{
    __shared__ int sc[256], degs[256], lb[256], cur[256];
    __shared__ ushort sorted[6400];
    int tid = threadIdx.x, h = blockIdx.x;
    int dv = (tid < NH) ? dtot[tid] : 0;
    (void)exscan256(sc, tid, dv);           // sc = inclusive scan of dtot
    int start = (h == 0) ? 0 : sc[h - 1];
    int end   = sc[h];
    degs[tid] = 0;
    __syncthreads();
    for (int e = start + tid; e < end; e += 256)
        atomicAdd(&degs[(buf1[e] >> 16) & 255], 1);
    __syncthreads();
    int lbv = exscan256(sc, tid, degs[tid]);
    lb[tid] = lbv; cur[tid] = lbv;
    int n = h * 256 + tid;
    if (n <= NN) rowptr[n] = start + lbv;
    __syncthreads();
    for (int e = start + tid; e < end; e += 256) {
        unsigned kk = buf1[e];
        int d = (int)((kk >> 16) & 255u);
        int lr = atomicAdd(&cur[d], 1);
        sorted[lr] = (ushort)(kk & 0xffffu);
    }
    __syncthreads();
    int sz = end - start;
    for (int i = tid; i < sz; i += 256)
        nbr16[start + i] = sorted[i];       // contiguous, coalesced
}

// ---------------- gather0: fp8 x input, one node per 8-lane group, 4-deep MLP ----------------
__global__ __launch_bounds__(256) void gather0_k(
    const unsigned char* __restrict__ x8, const int* __restrict__ rowptr,
    const ushort* __restrict__ nbr, ushort* __restrict__ agg0)
{
    int node = (blockIdx.x * 256 + threadIdx.x) >> 3;
    int sub  = threadIdx.x & 7;
    if (node >= NN) return;
    int b = rowptr[node], e2 = rowptr[node + 1];
    float acc[8];
    #pragma unroll
    for (int j = 0; j < 8; ++j) acc[j] = 0.f;

    int e = b;
    for (; e + 4 <= e2; e += 4) {
        int s0 = nbr[e], s1 = nbr[e + 1], s2 = nbr[e + 2], s3 = nbr[e + 3];
        uint2 w0 = *(const uint2*)(x8 + s0 * 64 + sub * 8);
        uint2 w1 = *(const uint2*)(x8 + s1 * 64 + sub * 8);
        uint2 w2 = *(const uint2*)(x8 + s2 * 64 + sub * 8);
        uint2 w3 = *(const uint2*)(x8 + s3 * 64 + sub * 8);
        #pragma unroll
        for (int q = 0; q < 4; ++q) {
            uint2 w = (q == 0) ? w0 : (q == 1) ? w1 : (q == 2) ? w2 : w3;
            f32x2 f01 = __builtin_amdgcn_cvt_pk_f32_fp8(w.x, false);
            f32x2 f23 = __builtin_amdgcn_cvt_pk_f32_fp8(w.x, true);
            f32x2 f45 = __builtin_amdgcn_cvt_pk_f32_fp8(w.y, false);
            f32x2 f67 = __builtin_amdgcn_cvt_pk_f32_fp8(w.y, true);
            acc[0] += f01[0]; acc[1] += f01[1];
            acc[2] += f23[0]; acc[3] += f23[1];
            acc[4] += f45[0]; acc[5] += f45[1];
            acc[6] += f67[0]; acc[7] += f67[1];
        }
    }
    for (; e < e2; ++e) {
        int s = nbr[e];
        uint2 w = *(const uint2*)(x8 + s * 64 + sub * 8);
        f32x2 f01 = __builtin_amdgcn_cvt_pk_f32_fp8(w.x, false);
        f32x2 f23 = __builtin_amdgcn_cvt_pk_f32_fp8(w.x, true);
        f32x2 f45 = __builtin_amdgcn_cvt_pk_f32_fp8(w.y, false);
        f32x2 f67 = __builtin_amdgcn_cvt_pk_f32_fp8(w.y, true);
        acc[0] += f01[0]; acc[1] += f01[1];
        acc[2] += f23[0]; acc[3] += f23[1];
        acc[4] += f45[0]; acc[5] += f45[1];
        acc[6] += f67[0]; acc[7] += f67[1];
    }

    float inv = 1.0f / fmaxf((float)(e2 - b), 1.0f);
    short8 o;
    #pragma unroll
    for (int j = 0; j < 8; ++j) o[j] = (short)f2bf(acc[j] * inv);
    *(short8*)(agg0 + node * 64 + sub * 8) = o;
}

// ---------------- gather1: fp8 h8 input (permuted rows), one node per 16-lane group ----------------
__global__ __launch_bounds__(256) void gather1_k(
    const unsigned char* __restrict__ h8, const int* __restrict__ rowptr,
    const ushort* __restrict__ nbr, ushort* __restrict__ agg1)
{
    int node = (blockIdx.x * 256 + threadIdx.x) >> 4;
    int sub  = threadIdx.x & 15;
    if (node >= NN) return;
    int b = rowptr[node], e2 = rowptr[node + 1];
    float acc[8];
    #pragma unroll
    for (int j = 0; j < 8; ++j) acc[j] = 0.f;

    int e = b;
    for (; e + 4 <= e2; e += 4) {
        int s0 = nbr[e], s1 = nbr[e + 1], s2 = nbr[e + 2], s3 = nbr[e + 3];
        uint2 w0 = *(const uint2*)(h8 + s0 * 128 + sub * 8);
        uint2 w1 = *(const uint2*)(h8 + s1 * 128 + sub * 8);
        uint2 w2 = *(const uint2*)(h8 + s2 * 128 + sub * 8);
        uint2 w3 = *(const uint2*)(h8 + s3 * 128 + sub * 8);
        #pragma unroll
        for (int q = 0; q < 4; ++q) {
            uint2 w = (q == 0) ? w0 : (q == 1) ? w1 : (q == 2) ? w2 : w3;
            f32x2 f01 = __builtin_amdgcn_cvt_pk_f32_fp8(w.x, false);
            f32x2 f23 = __builtin_amdgcn_cvt_pk_f32_fp8(w.x, true);
            f32x2 f45 = __builtin_amdgcn_cvt_pk_f32_fp8(w.y, false);
            f32x2 f67 = __builtin_amdgcn_cvt_pk_f32_fp8(w.y, true);
            acc[0] += f01[0]; acc[1] += f01[1];
            acc[2] += f23[0]; acc[3] += f23[1];
            acc[4] += f45[0]; acc[5] += f45[1];
            acc[6] += f67[0]; acc[7] += f67[1];
        }
    }
    for (; e < e2; ++e) {
        int s = nbr[e];
        uint2 w = *(const uint2*)(h8 + s * 128 + sub * 8);
        f32x2 f01 = __builtin_amdgcn_cvt_pk_f32_fp8(w.x, false);
        f32x2 f23 = __builtin_amdgcn_cvt_pk_f32_fp8(w.x, true);
        f32x2 f45 = __builtin_amdgcn_cvt_pk_f32_fp8(w.y, false);
        f32x2 f67 = __builtin_amdgcn_cvt_pk_f32_fp8(w.y, true);
        acc[0] += f01[0]; acc[1] += f01[1];
        acc[2] += f23[0]; acc[3] += f23[1];
        acc[4] += f45[0]; acc[5] += f45[1];
        acc[6] += f67[0]; acc[7] += f67[1];
    }

    float inv = 1.0f / fmaxf((float)(e2 - b), 1.0f);
    #pragma unroll
    for (int j = 0; j < 8; ++j)
        agg1[node * 128 + j * 16 + sub] = f2bf(acc[j] * inv);
}

// ---------------- dense0: h0 = relu([agg0|x] @ [Wl0;Wr0]^T + bl0), MFMA + fp8 emit ----------------
__global__ __launch_bounds__(256) void dense0_k(
    const ushort* __restrict__ xb, const ushort* __restrict__ agg0,
    const ushort* __restrict__ wbt0, const float* __restrict__ bl,
    ushort* __restrict__ h0, unsigned char* __restrict__ h8)
{
    __shared__ ushort bt[128 * 128];
    __shared__ float  bl_s[128];

    #pragma unroll
    for (int c = 0; c < 8; ++c) {
        int i = threadIdx.x + c * 256;
        ((short8*)bt)[i] = ((const short8*)wbt0)[i];
    }
    if (threadIdx.x < 128) bl_s[threadIdx.x] = bl[threadIdx.x];
    __syncthreads();

    int w = threadIdx.x >> 6, l = threadIdx.x & 63;
    int l15 = l & 15, hi = l >> 4;
    int row  = blockIdx.x * 64 + w * 16 + l15;
    int rowc = row < NN ? row : 0;

    short8 a[4];
    a[0] = *(const short8*)(agg0 + rowc * 64 + hi * 8);
    a[1] = *(const short8*)(agg0 + rowc * 64 + 32 + hi * 8);
    a[2] = *(const short8*)(xb + rowc * 64 + hi * 8);
    a[3] = *(const short8*)(xb + rowc * 64 + 32 + hi * 8);

    f32x4 acc[8];
    #pragma unroll
    for (int nt = 0; nt < 8; ++nt) acc[nt] = (f32x4){0.f, 0.f, 0.f, 0.f};

    #pragma unroll
    for (int ks = 0; ks < 4; ++ks) {
        #pragma unroll
        for (int nt = 0; nt < 8; ++nt) {
            int byte = ((nt * 16 + l15) * 256 + (ks * 32 + hi * 8) * 2) ^ ((l15 & 7) << 4);
            short8 bfr = *(const short8*)((const char*)bt + byte);
            acc[nt] = __builtin_amdgcn_mfma_f32_16x16x32_bf16(a[ks], bfr, acc[nt], 0, 0, 0);
        }
    }

    int rowbase = blockIdx.x * 64 + w * 16 + hi * 4;
    #pragma unroll
    for (int r = 0; r < 4; ++r) {
        int ro = rowbase + r;
        if (ro < NN) {
            float v[8];
            #pragma unroll
            for (int nt = 0; nt < 8; ++nt) {
                int col = nt * 16 + l15;
                v[nt] = fmaxf(acc[nt][r] + bl_s[col], 0.f);
                h0[ro * 128 + col] = f2bf(v[nt]);
            }
            unsigned lo = 0, hiw = 0;
            lo  = __builtin_amdgcn_cvt_pk_fp8_f32(v[0], v[1], lo, false);
            lo  = __builtin_amdgcn_cvt_pk_fp8_f32(v[2], v[3], lo, true);
            hiw = __builtin_amdgcn_cvt_pk_fp8_f32(v[4], v[5], hiw, false);
            hiw = __builtin_amdgcn_cvt_pk_fp8_f32(v[6], v[7], hiw, true);
            uint2 q; q.x = lo; q.y = hiw;
            *(uint2*)(h8 + ro * 128 + l15 * 8) = q;
        }
    }
}

// ---------------- dense1 + fc fused, bt staged in two 32KB k-halves ----------------
__global__ __launch_bounds__(256) void dense1_k(
    const ushort* __restrict__ h0, const ushort* __restrict__ agg1,
    const ushort* __restrict__ wbt1, const float* __restrict__ bl,
    const float* __restrict__ Wfc, const float* __restrict__ bfc,
    float* __restrict__ out)
{
    __shared__ ushort bt[128 * 128];
    __shared__ float  bl_s[128];
    __shared__ float  wfc_s[256];

    #pragma unroll
    for (int c = 0; c < 8; ++c) {
        int i = threadIdx.x + c * 256;
        ((short8*)bt)[i] = ((const short8*)wbt1)[i];
    }
    if (threadIdx.x < 128) bl_s[threadIdx.x] = bl[threadIdx.x];
    if (threadIdx.x < 256) wfc_s[threadIdx.x] = Wfc[threadIdx.x];
    __syncthreads();

    int w = threadIdx.x >> 6, l = threadIdx.x & 63;
    int l15 = l & 15, hi = l >> 4;
    int row  = blockIdx.x * 64 + w * 16 + l15;
    int rowc = row < NN ? row : 0;

    short8 a[8];
    #pragma unroll
    for (int ks = 0; ks < 4; ++ks)
        a[ks] = *(const short8*)(agg1 + rowc * 128 + ks * 32 + hi * 8);
    #pragma unroll
    for (int ks = 0; ks < 4; ++ks)
        a[4 + ks] = *(const short8*)(h0 + rowc * 128 + ks * 32 + hi * 8);

    f32x4 acc[8];
    #pragma unroll
    for (int nt = 0; nt < 8; ++nt) acc[nt] = (f32x4){0.f, 0.f, 0.f, 0.f};

    #pragma unroll
    for (int ks = 0; ks < 4; ++ks) {   // k-half 0: agg1 x Wl1
        #pragma unroll
        for (int nt = 0; nt < 8; ++nt) {
            int byte = ((nt * 16 + l15) * 256 + (ks * 32 + hi * 8) * 2) ^ ((l15 & 7) << 4);
            short8 bfr = *(const short8*)((const char*)bt + byte);
            acc[nt] = __builtin_amdgcn_mfma_f32_16x16x32_bf16(a[ks], bfr, acc[nt], 0, 0, 0);
        }
    }
    __syncthreads();
    #pragma unroll
    for (int c = 0; c < 8; ++c) {      // stage k-half 1 (Wr1)
        int i = threadIdx.x + c * 256;
        ((short8*)bt)[i] = ((const short8*)(wbt1 + 16384))[i];
    }
    __syncthreads();
    #pragma unroll
    for (int ks = 0; ks < 4; ++ks) {   // k-half 1: h0 x Wr1
        #pragma unroll
        for (int nt = 0; nt < 8; ++nt) {
            int byte = ((nt * 16 + l15) * 256 + (ks * 32 + hi * 8) * 2) ^ ((l15 & 7) << 4);
            short8 bfr = *(const short8*)((const char*)bt + byte);
            acc[nt] = __builtin_amdgcn_mfma_f32_16x16x32_bf16(a[4 + ks], bfr, acc[nt], 0, 0, 0);
        }
    }

    int rowbase = blockIdx.x * 64 + w * 16 + hi * 4;
    #pragma unroll
    for (int r = 0; r < 4; ++r) {
        float p0 = 0.f, p1 = 0.f;
        #pragma unroll
        for (int nt = 0; nt < 8; ++nt) {
            int col = nt * 16 + l15;
            float h1 = fmaxf(acc[nt][r] + bl_s[col], 0.f);
            p0 += h1 * wfc_s[col];
            p1 += h1 * wfc_s[128 + col];
        }
        p0 += __shfl_xor(p0, 1, 64); p0 += __shfl_xor(p0, 2, 64);
        p0 += __shfl_xor(p0, 4, 64); p0 += __shfl_xor(p0, 8, 64);
        p1 += __shfl_xor(p1, 1, 64); p1 += __shfl_xor(p1, 2, 64);
        p1 += __shfl_xor(p1, 4, 64); p1 += __shfl_xor(p1, 8, 64);
        int ro = rowbase + r;
        if (l15 == 0 && ro < NN) {
            float2 o; o.x = p0 + bfc[0]; o.y = p1 + bfc[1];
            *(float2*)(out + ro * 2) = o;
        }
    }
}

extern "C" void kernel_launch(void* const* d_in, const int* in_sizes, int n_in,
                              void* d_out, int out_size, void* d_ws, size_t ws_size,
                              hipStream_t stream)
{
    const float* x   = (const float*)d_in[0];
    const int*   ei  = (const int*)d_in[1];
    const float* Wl0 = (const float*)d_in[2];
    const float* bl0 = (const float*)d_in[3];
    const float* Wr0 = (const float*)d_in[4];
    const float* Wl1 = (const float*)d_in[5];
    const float* bl1 = (const float*)d_in[6];
    const float* Wr1 = (const float*)d_in[7];
    const float* Wfc = (const float*)d_in[8];
    const float* bfc = (const float*)d_in[9];
    float* out = (float*)d_out;

    const int* src = ei;
    const int* dst = ei + NE;

    // ws layout (bytes):
    //   buf1   @ 0          (3,200,000)
    //   nbr16  @ 3,200,000  (1,600,000)
    //   rowptr @ 4,800,000  (200,004)
    //   ghist  @ 5,000,016  (204,800)    [block][digit], 200x256
    //   gbase  @ 5,204,816  (204,800)
    //   dtot   @ 5,409,616  (1,024)
    //   aggB   @ 5,410,656  (12,800,000)
    //   h0B    @ 18,210,656 (12,800,000)
    //   xb     @ 31,010,656 (6,400,000)
    //   x8     @ 37,410,656 (3,200,000)
    //   wbt0   @ 40,610,656 (32,768)
    //   wbt1   @ 40,643,424 (65,536)
    //   h8     @ 40,708,960 (6,400,000)
    char*     ws     = (char*)d_ws;
    unsigned* buf1   = (unsigned*)(ws);
    ushort*   nbr16  = (ushort*)(ws + 3200000);
    int*      rowptr = (int*)(ws + 4800000);
    int*      ghist  = (int*)(ws + 5000016);
    int*      gbase  = (int*)(ws + 5204816);
    int*      dtot   = (int*)(ws + 5409616);
    ushort*   aggB   = (ushort*)(ws + 5410656);
    ushort*   h0B    = (ushort*)(ws + 18210656);
    ushort*   xb     = (ushort*)(ws + 31010656);
    unsigned* x8w    = (unsigned*)(ws + 37410656);
    ushort*   wbt0   = (ushort*)(ws + 40610656);
    ushort*   wbt1   = (ushort*)(ws + 40643424);
    unsigned char* h8 = (unsigned char*)(ws + 40708960);

    hist1_k<<<NBK, 256, 0, stream>>>(dst, ghist);
    scan1_k<<<NH, 256, 0, stream>>>(ghist, gbase, dtot, x, xb, x8w,
                                    Wl0, Wr0, Wl1, Wr1, wbt0, wbt1);
    scat1_k<<<NBK, 256, 0, stream>>>(src, dst, gbase, dtot, buf1);
    build_k<<<NH, 256, 0, stream>>>(buf1, dtot, rowptr, nbr16);

    gather0_k<<<1563, 256, 0, stream>>>((const unsigned char*)x8w, rowptr, nbr16, aggB);
    dense0_k <<<782, 256, 0, stream>>>(xb, aggB, wbt0, bl0, h0B, h8);
    gather1_k<<<3125, 256, 0, stream>>>(h8, rowptr, nbr16, aggB);
    dense1_k <<<782, 256, 0, stream>>>(h0B, aggB, wbt1, bl1, Wfc, bfc, out);
}

// Round 21
// 91.865 us; speedup vs baseline: 1.0475x; 1.0475x over previous
//
#include <hip/hip_runtime.h>
#include <hip/hip_bf16.h>

#define NN   50000
#define NE   800000
#define NBK  625    // partition blocks, 1280 edges each (625*1280 == NE exactly)
#define NH   196    // MSD buckets: h = dst >> 8, h in [0,196)

typedef __attribute__((ext_vector_type(8))) short short8;
typedef __attribute__((ext_vector_type(4))) float f32x4;
typedef __attribute__((ext_vector_type(2))) float f32x2;

static __device__ __forceinline__ ushort f2bf(float f) {
    union { float f; unsigned u; } v; v.f = f;
    unsigned r = v.u + 0x7fffu + ((v.u >> 16) & 1u);   // round-to-nearest-even
    return (ushort)(r >> 16);
}
static __device__ __forceinline__ float bf2f(ushort h) {
    union { unsigned u; float f; } v; v.u = ((unsigned)h) << 16;
    return v.f;
}

// exclusive scan of 256 values; on return s[] holds INCLUSIVE scan.
static __device__ __forceinline__ int exscan256(int* s, int tid, int v) {
    __syncthreads();
    s[tid] = v;
    __syncthreads();
    #pragma unroll
    for (int off = 1; off < 256; off <<= 1) {
        int a = (tid >= off) ? s[tid - off] : 0;
        __syncthreads();
        s[tid] += a;
        __syncthreads();
    }
    return s[tid] - v;
}

// ---------------- hist1: per-block histogram of h=dst>>8 + cvtx + weight prep ----------------
// 625 blocks x 256. Block b owns edges [b*1280, b*1280+1280).
__global__ __launch_bounds__(256) void hist1_k(
    const int* __restrict__ dst, int* __restrict__ ghist,
    const float* __restrict__ x, ushort* __restrict__ xb,
    unsigned* __restrict__ x8w,
    const float* __restrict__ Wl0, const float* __restrict__ Wr0,
    const float* __restrict__ Wl1, const float* __restrict__ Wr1,
    ushort* __restrict__ wbt0, ushort* __restrict__ wbt1)
{
    __shared__ int hist[256];
    int tid = threadIdx.x, b = blockIdx.x;
    int gid = b * 256 + tid;
    hist[tid] = 0;

    if (gid < 2048) {
        {   // dense0 image
            int c = gid;
            int n  = c >> 4;
            int kc = (c & 15) * 8;
            const float* wsrc = (kc < 64) ? (Wl0 + n * 64 + kc) : (Wr0 + n * 64 + (kc - 64));
            float4 f0 = *(const float4*)(wsrc);
            float4 f1 = *(const float4*)(wsrc + 4);
            short8 v;
            v[0] = f2bf(f0.x); v[1] = f2bf(f0.y); v[2] = f2bf(f0.z); v[3] = f2bf(f0.w);
            v[4] = f2bf(f1.x); v[5] = f2bf(f1.y); v[6] = f2bf(f1.z); v[7] = f2bf(f1.w);
            int byte = (n * 256 + kc * 2) ^ ((n & 7) << 4);
            *(short8*)((char*)wbt0 + byte) = v;
        }
        #pragma unroll
        for (int rep = 0; rep < 2; ++rep) {   // dense1 half-images
            int c = gid + rep * 2048;
            int n  = c >> 5;
            int kc = (c & 31) * 8;
            int h  = (kc >= 128);
            int kk = kc - h * 128;
            const float* wsrc = h ? (Wr1 + n * 128 + kk) : (Wl1 + n * 128 + kk);
            float4 f0 = *(const float4*)(wsrc);
            float4 f1 = *(const float4*)(wsrc + 4);
            short8 v;
            v[0] = f2bf(f0.x); v[1] = f2bf(f0.y); v[2] = f2bf(f0.z); v[3] = f2bf(f0.w);
            v[4] = f2bf(f1.x); v[5] = f2bf(f1.y); v[6] = f2bf(f1.z); v[7] = f2bf(f1.w);
            int byte = h * 32768 + ((n * 256 + kk * 2) ^ ((n & 7) << 4));
            *(short8*)((char*)wbt1 + byte) = v;
        }
    }

    // cvtx: 5 coalesced float4 rounds -> bf16 + fp8 (160000 threads x 20 floats)
    #pragma unroll
    for (int k5 = 0; k5 < 5; ++k5) {
        int idx = k5 * 160000 + gid;       // float4-group index, < 800000
        float4 f = ((const float4*)x)[idx];
        ushort4 o;
        o.x = f2bf(f.x); o.y = f2bf(f.y); o.z = f2bf(f.z); o.w = f2bf(f.w);
        ((ushort4*)xb)[idx] = o;
        unsigned q = 0;
        q = __builtin_amdgcn_cvt_pk_fp8_f32(f.x, f.y, q, false);
        q = __builtin_amdgcn_cvt_pk_fp8_f32(f.z, f.w, q, true);
        x8w[idx] = q;
    }

    __syncthreads();
    int eb = b * 1280;
    #pragma unroll
    for (int j = 0; j < 5; ++j) {
        int e = eb + j * 256 + tid;
        atomicAdd(&hist[dst[e] >> 8], 1);
    }
    __syncthreads();
    ghist[b * 256 + tid] = hist[tid];
}

// ---------------- scan1: per-digit exclusive scan over the 625 blocks ----------------
// 196 blocks, block h scans ghist[b][h] over b.
__global__ __launch_bounds__(256) void scan1_k(
    const int* __restrict__ ghist, int* __restrict__ gbase,
    int* __restrict__ dtot)
{
    __shared__ int s[256];
    int tid = threadIdx.x, h = blockIdx.x;
    int carry = 0;
    for (int c = 0; c < 3; ++c) {
        int idx = c * 256 + tid;
        int v = (idx < NBK) ? ghist[idx * 256 + h] : 0;
        int ex = exscan256(s, tid, v);
        if (idx < NBK) gbase[idx * 256 + h] = carry + ex;
        carry += s[255];
        __syncthreads();
    }
    if (tid == 0) dtot[h] = carry;
}

// ---------------- scat1: partition packed edges by h into buf1 (LDS local sort) ----------------
__global__ __launch_bounds__(256) void scat1_k(
    const int* __restrict__ src, const int* __restrict__ dst,
    const int* __restrict__ gbase, const int* __restrict__ dtot,
    unsigned* __restrict__ buf1)
{
    __shared__ int sc[256], hist[256], lbase[256], cur[256], dbase[256], gb[256];
    __shared__ unsigned sorted[1280];
    int tid = threadIdx.x, b = blockIdx.x;
    hist[tid] = 0;
    gb[tid] = gbase[b * 256 + tid];         // digits >=196 garbage but never used
    int dv = (tid < NH) ? dtot[tid] : 0;
    int eb = b * 1280;
    unsigned k[5]; int dg[5];
    __syncthreads();
    #pragma unroll
    for (int j = 0; j < 5; ++j) {
        int e = eb + j * 256 + tid;
        int d_ = dst[e];
        k[j]  = ((unsigned)d_ << 16) | (unsigned)src[e];
        dg[j] = d_ >> 8;
        atomicAdd(&hist[dg[j]], 1);
    }
    __syncthreads();
    int ex = exscan256(sc, tid, hist[tid]);
    lbase[tid] = ex; cur[tid] = ex;
    int dbx = exscan256(sc, tid, dv);
    dbase[tid] = dbx;
    __syncthreads();
    #pragma unroll
    for (int j = 0; j < 5; ++j) {
        int lr = atomicAdd(&cur[dg[j]], 1);
        sorted[lr] = k[j];
    }
    __syncthreads();
    #pragma unroll
    for (int j = 0; j < 5; ++j) {
        int i = j * 256 + tid;
        unsigned kk = sorted[i];
        int dig = (int)(kk >> 24);          // == dst >> 8
        int pos = dbase[dig] + gb[dig] + (i - lbase[dig]);
        buf1[pos] = kk;
    }
}

// ---------------- build: per-bucket LDS count/rank -> rowptr + nbr16 ----------------
// 196 blocks; bucket h covers nodes [h*256, h*256+256).
__global__ __launch_bounds__(256) void build_k(
    const unsigned* __restrict__ buf1, const int* __restrict__ dtot,
    int* __restrict__ rowptr, ushort* __restrict__ nbr16)
{
    __shared__ int sc[256], degs[256], lb[256], cur[256];
    __shared__ ushort sorted[6400];
    int tid = threadIdx.x, h = blockIdx.x;
    int dv = (tid < NH) ? dtot[tid] : 0;
    (void)exscan256(sc, tid, dv);           // sc = inclusive scan of dtot
    int start = (h == 0) ? 0 : sc[h - 1];
    int end   = sc[h];
    degs[tid] = 0;
    __syncthreads();
    for (int e = start + tid; e < end; e += 256)
        atomicAdd(&degs[(buf1[e] >> 16) & 255], 1);
    __syncthreads();
    int lbv = exscan256(sc, tid, degs[tid]);
    lb[tid] = lbv; cur[tid] = lbv;
    int n = h * 256 + tid;
    if (n <= NN) rowptr[n] = start + lbv;   // n==NN lands at block 195, tid 80 -> NE
    __syncthreads();
    for (int e = start + tid; e < end; e += 256) {
        unsigned kk = buf1[e];
        int d = (int)((kk >> 16) & 255u);
        int lr = atomicAdd(&cur[d], 1);
        sorted[lr] = (ushort)(kk & 0xffffu);
    }
    __syncthreads();
    int sz = end - start;
    for (int i = tid; i < sz; i += 256)
        nbr16[start + i] = sorted[i];       // contiguous, coalesced
}

// ---------------- gather0: fp8 x input, one node per 8-lane group, 4-deep MLP ----------------
__global__ __launch_bounds__(256) void gather0_k(
    const unsigned char* __restrict__ x8, const int* __restrict__ rowptr,
    const ushort* __restrict__ nbr, ushort* __restrict__ agg0)
{
    int node = (blockIdx.x * 256 + threadIdx.x) >> 3;
    int sub  = threadIdx.x & 7;
    if (node >= NN) return;
    int b = rowptr[node], e2 = rowptr[node + 1];
    float acc[8];
    #pragma unroll
    for (int j = 0; j < 8; ++j) acc[j] = 0.f;

    int e = b;
    for (; e + 4 <= e2; e += 4) {
        int s0 = nbr[e], s1 = nbr[e + 1], s2 = nbr[e + 2], s3 = nbr[e + 3];
        uint2 w0 = *(const uint2*)(x8 + s0 * 64 + sub * 8);
        uint2 w1 = *(const uint2*)(x8 + s1 * 64 + sub * 8);
        uint2 w2 = *(const uint2*)(x8 + s2 * 64 + sub * 8);
        uint2 w3 = *(const uint2*)(x8 + s3 * 64 + sub * 8);
        #pragma unroll
        for (int q = 0; q < 4; ++q) {
            uint2 w = (q == 0) ? w0 : (q == 1) ? w1 : (q == 2) ? w2 : w3;
            f32x2 f01 = __builtin_amdgcn_cvt_pk_f32_fp8(w.x, false);
            f32x2 f23 = __builtin_amdgcn_cvt_pk_f32_fp8(w.x, true);
            f32x2 f45 = __builtin_amdgcn_cvt_pk_f32_fp8(w.y, false);
            f32x2 f67 = __builtin_amdgcn_cvt_pk_f32_fp8(w.y, true);
            acc[0] += f01[0]; acc[1] += f01[1];
            acc[2] += f23[0]; acc[3] += f23[1];
            acc[4] += f45[0]; acc[5] += f45[1];
            acc[6] += f67[0]; acc[7] += f67[1];
        }
    }
    for (; e < e2; ++e) {
        int s = nbr[e];
        uint2 w = *(const uint2*)(x8 + s * 64 + sub * 8);
        f32x2 f01 = __builtin_amdgcn_cvt_pk_f32_fp8(w.x, false);
        f32x2 f23 = __builtin_amdgcn_cvt_pk_f32_fp8(w.x, true);
        f32x2 f45 = __builtin_amdgcn_cvt_pk_f32_fp8(w.y, false);
        f32x2 f67 = __builtin_amdgcn_cvt_pk_f32_fp8(w.y, true);
        acc[0] += f01[0]; acc[1] += f01[1];
        acc[2] += f23[0]; acc[3] += f23[1];
        acc[4] += f45[0]; acc[5] += f45[1];
        acc[6] += f67[0]; acc[7] += f67[1];
    }

    float inv = 1.0f / fmaxf((float)(e2 - b), 1.0f);
    short8 o;
    #pragma unroll
    for (int j = 0; j < 8; ++j) o[j] = (short)f2bf(acc[j] * inv);
    *(short8*)(agg0 + node * 64 + sub * 8) = o;
}

// ---------------- gather1: fp8 h8 input (permuted rows), one node per 16-lane group ----------------
__global__ __launch_bounds__(256) void gather1_k(
    const unsigned char* __restrict__ h8, const int* __restrict__ rowptr,
    const ushort* __restrict__ nbr, ushort* __restrict__ agg1)
{
    int node = (blockIdx.x * 256 + threadIdx.x) >> 4;
    int sub  = threadIdx.x & 15;
    if (node >= NN) return;
    int b = rowptr[node], e2 = rowptr[node + 1];
    float acc[8];
    #pragma unroll
    for (int j = 0; j < 8; ++j) acc[j] = 0.f;

    int e = b;
    for (; e + 4 <= e2; e += 4) {
        int s0 = nbr[e], s1 = nbr[e + 1], s2 = nbr[e + 2], s3 = nbr[e + 3];
        uint2 w0 = *(const uint2*)(h8 + s0 * 128 + sub * 8);
        uint2 w1 = *(const uint2*)(h8 + s1 * 128 + sub * 8);
        uint2 w2 = *(const uint2*)(h8 + s2 * 128 + sub * 8);
        uint2 w3 = *(const uint2*)(h8 + s3 * 128 + sub * 8);
        #pragma unroll
        for (int q = 0; q < 4; ++q) {
            uint2 w = (q == 0) ? w0 : (q == 1) ? w1 : (q == 2) ? w2 : w3;
            f32x2 f01 = __builtin_amdgcn_cvt_pk_f32_fp8(w.x, false);
            f32x2 f23 = __builtin_amdgcn_cvt_pk_f32_fp8(w.x, true);
            f32x2 f45 = __builtin_amdgcn_cvt_pk_f32_fp8(w.y, false);
            f32x2 f67 = __builtin_amdgcn_cvt_pk_f32_fp8(w.y, true);
            acc[0] += f01[0]; acc[1] += f01[1];
            acc[2] += f23[0]; acc[3] += f23[1];
            acc[4] += f45[0]; acc[5] += f45[1];
            acc[6] += f67[0]; acc[7] += f67[1];
        }
    }
    for (; e < e2; ++e) {
        int s = nbr[e];
        uint2 w = *(const uint2*)(h8 + s * 128 + sub * 8);
        f32x2 f01 = __builtin_amdgcn_cvt_pk_f32_fp8(w.x, false);
        f32x2 f23 = __builtin_amdgcn_cvt_pk_f32_fp8(w.x, true);
        f32x2 f45 = __builtin_amdgcn_cvt_pk_f32_fp8(w.y, false);
        f32x2 f67 = __builtin_amdgcn_cvt_pk_f32_fp8(w.y, true);
        acc[0] += f01[0]; acc[1] += f01[1];
        acc[2] += f23[0]; acc[3] += f23[1];
        acc[4] += f45[0]; acc[5] += f45[1];
        acc[6] += f67[0]; acc[7] += f67[1];
    }

    float inv = 1.0f / fmaxf((float)(e2 - b), 1.0f);
    #pragma unroll
    for (int j = 0; j < 8; ++j)
        agg1[node * 128 + j * 16 + sub] = f2bf(acc[j] * inv);
}

// ---------------- dense0: h0 = relu([agg0|x] @ [Wl0;Wr0]^T + bl0), MFMA + fp8 emit ----------------
__global__ __launch_bounds__(256) void dense0_k(
    const ushort* __restrict__ xb, const ushort* __restrict__ agg0,
    const ushort* __restrict__ wbt0, const float* __restrict__ bl,
    ushort* __restrict__ h0, unsigned char* __restrict__ h8)
{
    __shared__ ushort bt[128 * 128];
    __shared__ float  bl_s[128];

    #pragma unroll
    for (int c = 0; c < 8; ++c) {
        int i = threadIdx.x + c * 256;
        ((short8*)bt)[i] = ((const short8*)wbt0)[i];
    }
    if (threadIdx.x < 128) bl_s[threadIdx.x] = bl[threadIdx.x];
    __syncthreads();

    int w = threadIdx.x >> 6, l = threadIdx.x & 63;
    int l15 = l & 15, hi = l >> 4;
    int row  = blockIdx.x * 64 + w * 16 + l15;
    int rowc = row < NN ? row : 0;

    short8 a[4];
    a[0] = *(const short8*)(agg0 + rowc * 64 + hi * 8);
    a[1] = *(const short8*)(agg0 + rowc * 64 + 32 + hi * 8);
    a[2] = *(const short8*)(xb + rowc * 64 + hi * 8);
    a[3] = *(const short8*)(xb + rowc * 64 + 32 + hi * 8);

    f32x4 acc[8];
    #pragma unroll
    for (int nt = 0; nt < 8; ++nt) acc[nt] = (f32x4){0.f, 0.f, 0.f, 0.f};

    #pragma unroll
    for (int ks = 0; ks < 4; ++ks) {
        #pragma unroll
        for (int nt = 0; nt < 8; ++nt) {
            int byte = ((nt * 16 + l15) * 256 + (ks * 32 + hi * 8) * 2) ^ ((l15 & 7) << 4);
            short8 bfr = *(const short8*)((const char*)bt + byte);
            acc[nt] = __builtin_amdgcn_mfma_f32_16x16x32_bf16(a[ks], bfr, acc[nt], 0, 0, 0);
        }
    }

    int rowbase = blockIdx.x * 64 + w * 16 + hi * 4;
    #pragma unroll
    for (int r = 0; r < 4; ++r) {
        int ro = rowbase + r;
        if (ro < NN) {
            float v[8];
            #pragma unroll
            for (int nt = 0; nt < 8; ++nt) {
                int col = nt * 16 + l15;
                v[nt] = fmaxf(acc[nt][r] + bl_s[col], 0.f);
                h0[ro * 128 + col] = f2bf(v[nt]);
            }
            unsigned lo = 0, hiw = 0;
            lo  = __builtin_amdgcn_cvt_pk_fp8_f32(v[0], v[1], lo, false);
            lo  = __builtin_amdgcn_cvt_pk_fp8_f32(v[2], v[3], lo, true);
            hiw = __builtin_amdgcn_cvt_pk_fp8_f32(v[4], v[5], hiw, false);
            hiw = __builtin_amdgcn_cvt_pk_fp8_f32(v[6], v[7], hiw, true);
            uint2 q; q.x = lo; q.y = hiw;
            *(uint2*)(h8 + ro * 128 + l15 * 8) = q;
        }
    }
}

// ---------------- dense1 + fc fused, bt staged in two 32KB k-halves ----------------
__global__ __launch_bounds__(256) void dense1_k(
    const ushort* __restrict__ h0, const ushort* __restrict__ agg1,
    const ushort* __restrict__ wbt1, const float* __restrict__ bl,
    const float* __restrict__ Wfc, const float* __restrict__ bfc,
    float* __restrict__ out)
{
    __shared__ ushort bt[128 * 128];
    __shared__ float  bl_s[128];
    __shared__ float  wfc_s[256];

    #pragma unroll
    for (int c = 0; c < 8; ++c) {
        int i = threadIdx.x + c * 256;
        ((short8*)bt)[i] = ((const short8*)wbt1)[i];
    }
    if (threadIdx.x < 128) bl_s[threadIdx.x] = bl[threadIdx.x];
    if (threadIdx.x < 256) wfc_s[threadIdx.x] = Wfc[threadIdx.x];
    __syncthreads();

    int w = threadIdx.x >> 6, l = threadIdx.x & 63;
    int l15 = l & 15, hi = l >> 4;
    int row  = blockIdx.x * 64 + w * 16 + l15;
    int rowc = row < NN ? row : 0;

    short8 a[8];
    #pragma unroll
    for (int ks = 0; ks < 4; ++ks)
        a[ks] = *(const short8*)(agg1 + rowc * 128 + ks * 32 + hi * 8);
    #pragma unroll
    for (int ks = 0; ks < 4; ++ks)
        a[4 + ks] = *(const short8*)(h0 + rowc * 128 + ks * 32 + hi * 8);

    f32x4 acc[8];
    #pragma unroll
    for (int nt = 0; nt < 8; ++nt) acc[nt] = (f32x4){0.f, 0.f, 0.f, 0.f};

    #pragma unroll
    for (int ks = 0; ks < 4; ++ks) {   // k-half 0: agg1 x Wl1
        #pragma unroll
        for (int nt = 0; nt < 8; ++nt) {
            int byte = ((nt * 16 + l15) * 256 + (ks * 32 + hi * 8) * 2) ^ ((l15 & 7) << 4);
            short8 bfr = *(const short8*)((const char*)bt + byte);
            acc[nt] = __builtin_amdgcn_mfma_f32_16x16x32_bf16(a[ks], bfr, acc[nt], 0, 0, 0);
        }
    }
    __syncthreads();
    #pragma unroll
    for (int c = 0; c < 8; ++c) {      // stage k-half 1 (Wr1)
        int i = threadIdx.x + c * 256;
        ((short8*)bt)[i] = ((const short8*)(wbt1 + 16384))[i];
    }
    __syncthreads();
    #pragma unroll
    for (int ks = 0; ks < 4; ++ks) {   // k-half 1: h0 x Wr1
        #pragma unroll
        for (int nt = 0; nt < 8; ++nt) {
            int byte = ((nt * 16 + l15) * 256 + (ks * 32 + hi * 8) * 2) ^ ((l15 & 7) << 4);
            short8 bfr = *(const short8*)((const char*)bt + byte);
            acc[nt] = __builtin_amdgcn_mfma_f32_16x16x32_bf16(a[4 + ks], bfr, acc[nt], 0, 0, 0);
        }
    }

    int rowbase = blockIdx.x * 64 + w * 16 + hi * 4;
    #pragma unroll
    for (int r = 0; r < 4; ++r) {
        float p0 = 0.f, p1 = 0.f;
        #pragma unroll
        for (int nt = 0; nt < 8; ++nt) {
            int col = nt * 16 + l15;
            float h1 = fmaxf(acc[nt][r] + bl_s[col], 0.f);
            p0 += h1 * wfc_s[col];
            p1 += h1 * wfc_s[128 + col];
        }
        p0 += __shfl_xor(p0, 1, 64); p0 += __shfl_xor(p0, 2, 64);
        p0 += __shfl_xor(p0, 4, 64); p0 += __shfl_xor(p0, 8, 64);
        p1 += __shfl_xor(p1, 1, 64); p1 += __shfl_xor(p1, 2, 64);
        p1 += __shfl_xor(p1, 4, 64); p1 += __shfl_xor(p1, 8, 64);
        int ro = rowbase + r;
        if (l15 == 0 && ro < NN) {
            float2 o; o.x = p0 + bfc[0]; o.y = p1 + bfc[1];
            *(float2*)(out + ro * 2) = o;
        }
    }
}

extern "C" void kernel_launch(void* const* d_in, const int* in_sizes, int n_in,
                              void* d_out, int out_size, void* d_ws, size_t ws_size,
                              hipStream_t stream)
{
    const float* x   = (const float*)d_in[0];
    const int*   ei  = (const int*)d_in[1];
    const float* Wl0 = (const float*)d_in[2];
    const float* bl0 = (const float*)d_in[3];
    const float* Wr0 = (const float*)d_in[4];
    const float* Wl1 = (const float*)d_in[5];
    const float* bl1 = (const float*)d_in[6];
    const float* Wr1 = (const float*)d_in[7];
    const float* Wfc = (const float*)d_in[8];
    const float* bfc = (const float*)d_in[9];
    float* out = (float*)d_out;

    const int* src = ei;
    const int* dst = ei + NE;

    // ws layout (bytes):
    //   buf1   @ 0          (3,200,000)  packed (dst<<16|src), bucket-partitioned
    //   nbr16  @ 3,200,000  (1,600,000)
    //   rowptr @ 4,800,000  (200,004)
    //   ghist  @ 5,000,016  (640,000)    [block][digit]
    //   gbase  @ 5,640,016  (640,000)
    //   dtot   @ 6,280,016  (1,024)
    //   aggB   @ 6,281,056  (12,800,000)
    //   h0B    @ 19,081,056 (12,800,000)
    //   xb     @ 31,881,056 (6,400,000)
    //   x8     @ 38,281,056 (3,200,000)
    //   wbt0   @ 41,481,056 (32,768)
    //   wbt1   @ 41,513,824 (65,536)
    //   h8     @ 41,579,360 (6,400,000)
    char*     ws     = (char*)d_ws;
    unsigned* buf1   = (unsigned*)(ws);
    ushort*   nbr16  = (ushort*)(ws + 3200000);
    int*      rowptr = (int*)(ws + 4800000);
    int*      ghist  = (int*)(ws + 5000016);
    int*      gbase  = (int*)(ws + 5640016);
    int*      dtot   = (int*)(ws + 6280016);
    ushort*   aggB   = (ushort*)(ws + 6281056);
    ushort*   h0B    = (ushort*)(ws + 19081056);
    ushort*   xb     = (ushort*)(ws + 31881056);
    unsigned* x8w    = (unsigned*)(ws + 38281056);
    ushort*   wbt0   = (ushort*)(ws + 41481056);
    ushort*   wbt1   = (ushort*)(ws + 41513824);
    unsigned char* h8 = (unsigned char*)(ws + 41579360);

    hist1_k<<<NBK, 256, 0, stream>>>(dst, ghist, x, xb, x8w,
                                     Wl0, Wr0, Wl1, Wr1, wbt0, wbt1);
    scan1_k<<<NH, 256, 0, stream>>>(ghist, gbase, dtot);
    scat1_k<<<NBK, 256, 0, stream>>>(src, dst, gbase, dtot, buf1);
    build_k<<<NH, 256, 0, stream>>>(buf1, dtot, rowptr, nbr16);

    gather0_k<<<1563, 256, 0, stream>>>((const unsigned char*)x8w, rowptr, nbr16, aggB);
    dense0_k <<<782, 256, 0, stream>>>(xb, aggB, wbt0, bl0, h0B, h8);
    gather1_k<<<3125, 256, 0, stream>>>(h8, rowptr, nbr16, aggB);
    dense1_k <<<782, 256, 0, stream>>>(h0B, aggB, wbt1, bl1, Wfc, bfc, out);
}